// Round 14
// baseline (36.299 us; speedup 1.0000x reference)
//
#include <hip/hip_runtime.h>

#define B_SZ 512
#define V_SZ 1024
#define K_SZ 64
#define C_SZ 2048
#define A_SZ 128
#define KM   192   // 3 matrices x 64 cols

#define LOG2E 1.4426950408889634f

// ---------------------------------------------------------------------------
// Kernel 1: partial GEMM, NO per-iteration LDS, small per-CU W-bytes.
// Grid 256 = 64 row-tiles x 4 v-quarters; 256 threads (4 waves).
// Wave w: v-chunk [vq*256 + w*64, +64), lane = k, all 3 matrices, 8 rows.
// Per 4-v iter: 8 uniform-addr float4 x-loads (HW coalesces to one 16B
// fetch each) + 12 coalesced W dwords + 96 FMA. acc[8][3] in VGPRs.
// One-time LDS reduce folds the 4 waves; partial sums (pre-bias, pre-exp)
// go to ws_part[vq][row][km]. k2 finishes (sum 4, +bias, exp).
// ---------------------------------------------------------------------------
__global__ __launch_bounds__(256) void gw_gemm_part(
    const float* __restrict__ x,
    const float* __restrict__ Wa, const float* __restrict__ Wb,
    const float* __restrict__ Wk, float* __restrict__ ws_part) {
  __shared__ float part[4][8][KM];   // 24KB

  const int tid = threadIdx.x;
  const int rt = blockIdx.x & 63;
  const int vq = blockIdx.x >> 6;
  const int w  = tid >> 6;
  const int k  = tid & 63;
  const int r0 = rt * 8;
  const int v0 = vq * 256 + w * 64;

  float acc[8][3];
#pragma unroll
  for (int r = 0; r < 8; ++r)
    acc[r][0] = acc[r][1] = acc[r][2] = 0.f;

#pragma unroll 2
  for (int v4 = 0; v4 < 16; ++v4) {
    const int v = v0 + v4 * 4;
    float4 xr[8];
#pragma unroll
    for (int r = 0; r < 8; ++r)
      xr[r] = *(const float4*)&x[(size_t)(r0 + r) * V_SZ + v];
#pragma unroll
    for (int j = 0; j < 4; ++j) {
      const float wa = Wa[(v + j) * K_SZ + k];   // 256B coalesced
      const float wb = Wb[(v + j) * K_SZ + k];
      const float wk = Wk[(v + j) * K_SZ + k];
#pragma unroll
      for (int r = 0; r < 8; ++r) {
        const float xv = (j == 0) ? xr[r].x : (j == 1) ? xr[r].y
                       : (j == 2) ? xr[r].z : xr[r].w;
        acc[r][0] = fmaf(xv, wa, acc[r][0]);
        acc[r][1] = fmaf(xv, wb, acc[r][1]);
        acc[r][2] = fmaf(xv, wk, acc[r][2]);
      }
    }
  }

#pragma unroll
  for (int r = 0; r < 8; ++r) {
    part[w][r][0 * 64 + k] = acc[r][0];
    part[w][r][1 * 64 + k] = acc[r][1];
    part[w][r][2 * 64 + k] = acc[r][2];
  }
  __syncthreads();

  // fold 4 waves; store 1536 partials (8 rows x 192 km)
  for (int i = tid; i < 8 * KM; i += 256) {
    const int r = i / KM;
    const int km = i - r * KM;
    const float s = part[0][r][km] + part[1][r][km] +
                    part[2][r][km] + part[3][r][km];
    ws_part[((size_t)vq * B_SZ + r0 + r) * KM + km] = s;
  }
}

// ---------------------------------------------------------------------------
// Kernel 2: 1024 blocks = 512 rows x 2 A-halves, 256 threads (4 blocks/CU
// so latency chains overlap). Sum 4 vq-partials + bias -> exp -> al/bn/kap;
// conservative cutoff CL (term <= 2^-150 beyond -> phi exactly 0); phi to
// LDS (+global, own c-half); window over [0,CL) text rows, own 64-col half.
// ---------------------------------------------------------------------------
__global__ __launch_bounds__(256) void gw_phi_window(
    const float* __restrict__ text, const float* __restrict__ ws_part,
    const float* __restrict__ prev_kappa,
    const float* __restrict__ ba, const float* __restrict__ bb,
    const float* __restrict__ bk,
    float* __restrict__ out_phi, float* __restrict__ out_kappa,
    float* __restrict__ out_window) {
  __shared__ float al[K_SZ];
  __shared__ float bn[K_SZ];     // -log2(e)*beta
  __shared__ float kap[K_SZ];
  __shared__ float bnd[K_SZ];
  __shared__ int cl_s;
  __shared__ float phi_s[C_SZ];
  __shared__ float4 red[16][16];

  const int tid = threadIdx.x;
  const int b = blockIdx.x >> 1;
  const int h = blockIdx.x & 1;

  if (tid < KM) {
    const float s = ws_part[((size_t)0 * B_SZ + b) * KM + tid] +
                    ws_part[((size_t)1 * B_SZ + b) * KM + tid] +
                    ws_part[((size_t)2 * B_SZ + b) * KM + tid] +
                    ws_part[((size_t)3 * B_SZ + b) * KM + tid];
    const int m = tid >> 6, kk = tid & 63;
    const float bias = ((m == 0) ? ba : (m == 1) ? bb : bk)[kk];
    const float e = expf(s + bias);
    if (m == 0) {
      al[kk] = e;
    } else if (m == 1) {
      bn[kk] = -LOG2E * e;
    } else {
      const float nk = prev_kappa[b * K_SZ + kk] + e;
      kap[kk] = nk;
      if (h == 0) out_kappa[b * K_SZ + kk] = nk;
    }
  }
  __syncthreads();

  if (tid < K_SZ) {
    const float num = 150.f + fmaxf(0.f, log2f(al[tid]));
    bnd[tid] = kap[tid] + sqrtf(num / (-bn[tid]));
  }
  __syncthreads();
  if (tid == 0) {
    float mx = 0.f;
    for (int i = 0; i < K_SZ; ++i) mx = fmaxf(mx, bnd[i]);
    mx = fminf(mx, (float)C_SZ);     // sanitizes inf -> full compute
    int cl = (int)mx + 1;
    cl = (cl + 15) & ~15;
    if (cl > C_SZ) cl = C_SZ;
    cl_s = cl;
  }
  __syncthreads();
  const int CL = cl_s;

  // phi_s for all c < CL (both halves compute; needed for window)
  for (int c = tid; c < CL; c += 256) {
    const float cf = (float)c;
    float s = 0.f;
#pragma unroll
    for (int kk = 0; kk < K_SZ; ++kk) {
      const float d = kap[kk] - cf;
      s += al[kk] * exp2f(bn[kk] * d * d);
    }
    phi_s[c] = s;
  }
  // zero-fill own 1024-c half (one float4 per thread)
  {
    float4* po = (float4*)(out_phi + (size_t)b * C_SZ);
    po[h * 256 + tid] = make_float4(0.f, 0.f, 0.f, 0.f);
  }
  __syncthreads();
  // scatter computed phi values in own half
  for (int c = tid; c < CL; c += 256)
    if ((c >> 10) == h) out_phi[(size_t)b * C_SZ + c] = phi_s[c];

  // window: own 64-col (16 float4) half of A
  {
    const float4* __restrict__ t4 =
        (const float4*)(text + (size_t)b * C_SZ * A_SZ);
    const int a4 = h * 16 + (tid & 15);
    const int cr = tid >> 4;            // 16 parallel c-rows
    float4 acc = make_float4(0.f, 0.f, 0.f, 0.f);
    for (int cc = cr; cc < CL; cc += 16) {
      const float p = phi_s[cc];
      const float4 t = t4[cc * 32 + a4];   // 256B coalesced per 16 lanes
      acc.x = fmaf(p, t.x, acc.x);
      acc.y = fmaf(p, t.y, acc.y);
      acc.z = fmaf(p, t.z, acc.z);
      acc.w = fmaf(p, t.w, acc.w);
    }
    red[cr][tid & 15] = acc;
  }
  __syncthreads();

  if (tid < 16) {
    float4 wv = red[0][tid];
#pragma unroll
    for (int i = 1; i < 16; ++i) {
      const float4 rr = red[i][tid];
      wv.x += rr.x; wv.y += rr.y; wv.z += rr.z; wv.w += rr.w;
    }
    ((float4*)(out_window + (size_t)b * A_SZ))[h * 16 + tid] = wv;
  }
}

extern "C" void kernel_launch(void* const* d_in, const int* in_sizes, int n_in,
                              void* d_out, int out_size, void* d_ws, size_t ws_size,
                              hipStream_t stream) {
  const float* x    = (const float*)d_in[0];
  const float* text = (const float*)d_in[1];
  const float* pk   = (const float*)d_in[2];
  const float* Wa   = (const float*)d_in[3];
  const float* ba   = (const float*)d_in[4];
  const float* Wb   = (const float*)d_in[5];
  const float* bb   = (const float*)d_in[6];
  const float* Wk   = (const float*)d_in[7];
  const float* bk   = (const float*)d_in[8];

  float* out        = (float*)d_out;
  float* out_phi    = out;                              // B*C
  float* out_kappa  = out + (size_t)B_SZ * C_SZ;        // B*K
  float* out_win    = out_kappa + (size_t)B_SZ * K_SZ;  // B*A

  float* ws_part    = (float*)d_ws;                     // 4*512*192*4 = 1.57MB

  gw_gemm_part<<<256, 256, 0, stream>>>(x, Wa, Wb, Wk, ws_part);
  gw_phi_window<<<1024, 256, 0, stream>>>(text, ws_part, pk, ba, bb, bk,
                                          out_phi, out_kappa, out_win);
}

// Round 15
// 20.529 us; speedup vs baseline: 1.7682x; 1.7682x over previous
//
#include <hip/hip_runtime.h>
#include <hip/hip_bf16.h>

#define B_SZ 512
#define V_SZ 1024
#define K_SZ 64
#define C_SZ 2048
#define A_SZ 128
#define KM   192          // 3 mats x 64 cols
#define KH_STRIDE (B_SZ * KM)   // 98304

#define LOG2E 1.4426950408889634f

using short8 = __attribute__((ext_vector_type(8))) short;
using f32x4  = __attribute__((ext_vector_type(4))) float;

__device__ __forceinline__ unsigned short bf16c(float f) {
  unsigned u = __float_as_uint(f);
  return (unsigned short)((u + 0x7FFFu + ((u >> 16) & 1u)) >> 16);  // RNE
}

// ---------------------------------------------------------------------------
// Kernel 1: bf16 MFMA GEMM, partial over K-halves.
// Grid 768 = 32 mt x 12 nt x 2 kh; 64 threads (1 wave).
// LDS: X-tile [16 rows][512k +8 pad] bf16 (natural), WT-tile [16 km][512k+8]
// (transposed on stage). Frag reads: short8 b128, 2-way banks (pad 1040B).
// 16 x mfma_f32_16x16x32_bf16 chained into f32x4 acc (one K-half).
// D layout (m89): col = lane&15 -> batch-row, row = (lane>>4)*4+j -> km.
// Partials (pre-bias, pre-exp) to ws[kh][brow][km]; k2 finishes.
// ---------------------------------------------------------------------------
__global__ __launch_bounds__(64) void gw_gemm_mfma(
    const float* __restrict__ x,
    const float* __restrict__ Wa, const float* __restrict__ Wb,
    const float* __restrict__ Wk, float* __restrict__ wsp) {
  __shared__ unsigned short XT[16][520];   // 16.6 KB
  __shared__ unsigned short WT[16][520];   // 16.6 KB

  const int l  = threadIdx.x;
  const int bx = blockIdx.x;
  const int kh = bx & 1;
  const int nt = (bx >> 1) % 12;
  const int mt = bx / 24;

  const float* __restrict__ Wsrc = (nt < 4) ? Wa : (nt < 8) ? Wb : Wk;
  const int cb = (nt & 3) * 16;            // col base within the 64-wide W

  // ---- stage X-tile: 16 rows x 512 k (2 passes/row), coalesced f4 ----
#pragma unroll 4
  for (int p = 0; p < 32; ++p) {
    const int r = p >> 1;
    const int c0 = (p & 1) * 256 + l * 4;
    const float4 v =
        *(const float4*)&x[(size_t)(mt * 16 + r) * V_SZ + kh * 512 + c0];
    XT[r][c0 + 0] = bf16c(v.x);
    XT[r][c0 + 1] = bf16c(v.y);
    XT[r][c0 + 2] = bf16c(v.z);
    XT[r][c0 + 3] = bf16c(v.w);
  }
  // ---- stage W-tile transposed: src [k][16 cols] -> WT[col][k] ----
#pragma unroll 4
  for (int p = 0; p < 32; ++p) {
    const int flat = p * 64 + l;           // 0..2047
    const int k  = flat >> 2;              // 0..511
    const int c4 = flat & 3;               // f4 group within the 16 cols
    const float4 v =
        *(const float4*)&Wsrc[(size_t)(kh * 512 + k) * K_SZ + cb + c4 * 4];
    WT[c4 * 4 + 0][k] = bf16c(v.x);
    WT[c4 * 4 + 1][k] = bf16c(v.y);
    WT[c4 * 4 + 2][k] = bf16c(v.z);
    WT[c4 * 4 + 3][k] = bf16c(v.w);
  }
  __syncthreads();

  // ---- MFMA chain: A = WT (m=km on lane&15), B = XT (n=brow on lane&15) ----
  const int fr = l & 15;                   // frag row/col index
  const int q  = l >> 4;                   // k-chunk quarter
  f32x4 acc = {0.f, 0.f, 0.f, 0.f};
#pragma unroll
  for (int kc = 0; kc < 16; ++kc) {
    const int ko = kc * 32 + q * 8;
    short8 a = *(const short8*)&WT[fr][ko];
    short8 b = *(const short8*)&XT[fr][ko];
    acc = __builtin_amdgcn_mfma_f32_16x16x32_bf16(a, b, acc, 0, 0, 0);
  }

  // ---- epilogue: D[km][brow]; col(lane&15)=brow, row(q*4+j)=km ----
  const int brow = mt * 16 + fr;
#pragma unroll
  for (int j = 0; j < 4; ++j) {
    const int km = nt * 16 + q * 4 + j;
    wsp[kh * KH_STRIDE + brow * KM + km] = acc[j];
  }
}

// ---------------------------------------------------------------------------
// Kernel 2 (R4-proven structure): one block (512 thr) per batch row.
// Prologue: sum 2 K-half partials + bias -> exp -> al/bn/kap (+out_kappa).
// Then: conservative cutoff CL (term <= 2^-150 beyond -> phi exactly 0),
// phi -> LDS+global, exact zeros beyond, window = phi[0:CL) @ text[0:CL).
// ---------------------------------------------------------------------------
__global__ __launch_bounds__(512) void gw_phi_window(
    const float* __restrict__ text, const float* __restrict__ wsp,
    const float* __restrict__ prev_kappa,
    const float* __restrict__ ba, const float* __restrict__ bb,
    const float* __restrict__ bk,
    float* __restrict__ out_phi, float* __restrict__ out_kappa,
    float* __restrict__ out_window) {
  __shared__ float al[K_SZ];
  __shared__ float bn[K_SZ];     // -log2(e)*beta
  __shared__ float kap[K_SZ];
  __shared__ float bnd[K_SZ];
  __shared__ int cl_s;
  __shared__ float phi_s[C_SZ];
  __shared__ float4 red[16][32];

  const int tid = threadIdx.x;
  const int b = blockIdx.x;

  if (tid < KM) {
    const float s = wsp[b * KM + tid] + wsp[KH_STRIDE + b * KM + tid];
    const int m = tid >> 6, kk = tid & 63;
    const float bias = ((m == 0) ? ba : (m == 1) ? bb : bk)[kk];
    const float e = expf(s + bias);
    if (m == 0) {
      al[kk] = e;
    } else if (m == 1) {
      bn[kk] = -LOG2E * e;
    } else {
      const float nk = prev_kappa[b * K_SZ + kk] + e;
      kap[kk] = nk;
      out_kappa[b * K_SZ + kk] = nk;
    }
  }
  __syncthreads();

  if (tid < K_SZ) {
    const float num = 150.f + fmaxf(0.f, log2f(al[tid]));
    bnd[tid] = kap[tid] + sqrtf(num / (-bn[tid]));
  }
  __syncthreads();
  if (tid == 0) {
    float mx = 0.f;
    for (int i = 0; i < K_SZ; ++i) mx = fmaxf(mx, bnd[i]);
    mx = fminf(mx, (float)C_SZ);     // sanitizes inf -> full compute
    int cl = (int)mx + 1;
    cl = (cl + 15) & ~15;
    if (cl > C_SZ) cl = C_SZ;
    cl_s = cl;
  }
  __syncthreads();
  const int CL = cl_s;

  // ---- phi for c < CL ----
  for (int c = tid; c < CL; c += 512) {
    const float cf = (float)c;
    float s = 0.f;
#pragma unroll
    for (int k = 0; k < K_SZ; ++k) {
      const float d = kap[k] - cf;
      s += al[k] * exp2f(bn[k] * d * d);
    }
    phi_s[c] = s;
    out_phi[(size_t)b * C_SZ + c] = s;
  }
  // ---- exact zeros for c >= CL ----
  {
    float4 z = make_float4(0.f, 0.f, 0.f, 0.f);
    float4* po = (float4*)(out_phi + (size_t)b * C_SZ);
    for (int i = (CL >> 2) + tid; i < C_SZ / 4; i += 512) po[i] = z;
  }
  __syncthreads();

  // ---- window over [0, CL) rows of text ----
  const float4* __restrict__ t4 =
      (const float4*)(text + (size_t)b * C_SZ * A_SZ);
  const int a4 = tid & 31;   // float4 column (covers A=128)
  const int cr = tid >> 5;   // 16 parallel c-rows

  float4 acc = make_float4(0.f, 0.f, 0.f, 0.f);
  for (int cc = cr; cc < CL; cc += 16) {
    const float p = phi_s[cc];
    const float4 t = t4[cc * 32 + a4];   // coalesced 512B per row
    acc.x = fmaf(p, t.x, acc.x);
    acc.y = fmaf(p, t.y, acc.y);
    acc.z = fmaf(p, t.z, acc.z);
    acc.w = fmaf(p, t.w, acc.w);
  }

  red[cr][a4] = acc;
  __syncthreads();

  if (tid < 32) {
    float4 w = red[0][tid];
#pragma unroll
    for (int i = 1; i < 16; ++i) {
      const float4 r = red[i][tid];
      w.x += r.x; w.y += r.y; w.z += r.z; w.w += r.w;
    }
    ((float4*)(out_window + (size_t)b * A_SZ))[tid] = w;
  }
}

extern "C" void kernel_launch(void* const* d_in, const int* in_sizes, int n_in,
                              void* d_out, int out_size, void* d_ws, size_t ws_size,
                              hipStream_t stream) {
  const float* x    = (const float*)d_in[0];
  const float* text = (const float*)d_in[1];
  const float* pk   = (const float*)d_in[2];
  const float* Wa   = (const float*)d_in[3];
  const float* ba   = (const float*)d_in[4];
  const float* Wb   = (const float*)d_in[5];
  const float* bb   = (const float*)d_in[6];
  const float* Wk   = (const float*)d_in[7];
  const float* bk   = (const float*)d_in[8];

  float* out        = (float*)d_out;
  float* out_phi    = out;                              // B*C
  float* out_kappa  = out + (size_t)B_SZ * C_SZ;        // B*K
  float* out_win    = out_kappa + (size_t)B_SZ * K_SZ;  // B*A

  float* wsp        = (float*)d_ws;                     // 2*512*192*4 = 786KB

  gw_gemm_mfma<<<768, 64, 0, stream>>>(x, Wa, Wb, Wk, wsp);
  gw_phi_window<<<B_SZ, 512, 0, stream>>>(text, wsp, pk, ba, bb, bk,
                                          out_phi, out_kappa, out_win);
}

// Round 16
// 15.769 us; speedup vs baseline: 2.3020x; 1.3019x over previous
//
#include <hip/hip_runtime.h>
#include <hip/hip_bf16.h>

#define B_SZ 512
#define V_SZ 1024
#define K_SZ 64
#define C_SZ 2048
#define A_SZ 128
#define KM   192          // 3 mats x 64 cols
#define KH_STRIDE (B_SZ * KM)   // 98304

#define LOG2E 1.4426950408889634f

using short8 = __attribute__((ext_vector_type(8))) short;
using f32x4  = __attribute__((ext_vector_type(4))) float;

__device__ __forceinline__ unsigned short bf16c(float f) {
  unsigned u = __float_as_uint(f);
  return (unsigned short)((u + 0x7FFFu + ((u >> 16) & 1u)) >> 16);  // RNE
}

// ---------------------------------------------------------------------------
// Kernel 1 (verbatim R15, proven): bf16 MFMA GEMM, partial over K-halves.
// Grid 768 = 32 mt x 12 nt x 2 kh; 64 threads (1 wave).
// ---------------------------------------------------------------------------
__global__ __launch_bounds__(64) void gw_gemm_mfma(
    const float* __restrict__ x,
    const float* __restrict__ Wa, const float* __restrict__ Wb,
    const float* __restrict__ Wk, float* __restrict__ wsp) {
  __shared__ unsigned short XT[16][520];   // 16.6 KB
  __shared__ unsigned short WT[16][520];   // 16.6 KB

  const int l  = threadIdx.x;
  const int bx = blockIdx.x;
  const int kh = bx & 1;
  const int nt = (bx >> 1) % 12;
  const int mt = bx / 24;

  const float* __restrict__ Wsrc = (nt < 4) ? Wa : (nt < 8) ? Wb : Wk;
  const int cb = (nt & 3) * 16;            // col base within the 64-wide W

#pragma unroll 4
  for (int p = 0; p < 32; ++p) {
    const int r = p >> 1;
    const int c0 = (p & 1) * 256 + l * 4;
    const float4 v =
        *(const float4*)&x[(size_t)(mt * 16 + r) * V_SZ + kh * 512 + c0];
    XT[r][c0 + 0] = bf16c(v.x);
    XT[r][c0 + 1] = bf16c(v.y);
    XT[r][c0 + 2] = bf16c(v.z);
    XT[r][c0 + 3] = bf16c(v.w);
  }
#pragma unroll 4
  for (int p = 0; p < 32; ++p) {
    const int flat = p * 64 + l;           // 0..2047
    const int k  = flat >> 2;              // 0..511
    const int c4 = flat & 3;               // f4 group within the 16 cols
    const float4 v =
        *(const float4*)&Wsrc[(size_t)(kh * 512 + k) * K_SZ + cb + c4 * 4];
    WT[c4 * 4 + 0][k] = bf16c(v.x);
    WT[c4 * 4 + 1][k] = bf16c(v.y);
    WT[c4 * 4 + 2][k] = bf16c(v.z);
    WT[c4 * 4 + 3][k] = bf16c(v.w);
  }
  __syncthreads();

  const int fr = l & 15;
  const int q  = l >> 4;
  f32x4 acc = {0.f, 0.f, 0.f, 0.f};
#pragma unroll
  for (int kc = 0; kc < 16; ++kc) {
    const int ko = kc * 32 + q * 8;
    short8 a = *(const short8*)&WT[fr][ko];
    short8 b = *(const short8*)&XT[fr][ko];
    acc = __builtin_amdgcn_mfma_f32_16x16x32_bf16(a, b, acc, 0, 0, 0);
  }

  const int brow = mt * 16 + fr;
#pragma unroll
  for (int j = 0; j < 4; ++j) {
    const int km = nt * 16 + q * 4 + j;
    wsp[kh * KH_STRIDE + brow * KM + km] = acc[j];
  }
}

// ---------------------------------------------------------------------------
// Kernel 2 (latency-flattened): one block (512 thr) per batch row.
//  - prologue: sum 2 K-half partials + bias -> exp -> al/bn/kap (+out_kappa)
//  - cutoff: wave-0 shfl-xor max (no serial loop)
//  - T14: issue the 3 window text loads into regs BEFORE phi (HBM latency
//    hides under phi's VALU phase)
//  - phi: 4-way k-parallel (c = tid&127, kc = tid>>7), 128-thread finisher
//  - window: FMA from preloaded regs + tail loop; LDS reduce as proven
// ---------------------------------------------------------------------------
__global__ __launch_bounds__(512) void gw_phi_window(
    const float* __restrict__ text, const float* __restrict__ wsp,
    const float* __restrict__ prev_kappa,
    const float* __restrict__ ba, const float* __restrict__ bb,
    const float* __restrict__ bk,
    float* __restrict__ out_phi, float* __restrict__ out_kappa,
    float* __restrict__ out_window) {
  __shared__ float al[K_SZ];
  __shared__ float bn[K_SZ];     // -log2(e)*beta
  __shared__ float kap[K_SZ];
  __shared__ int cl_s;
  __shared__ float pp[4][128];   // partial phi [kchunk][c]
  __shared__ float phi_s[C_SZ];
  __shared__ float4 red[16][32];

  const int tid = threadIdx.x;
  const int b = blockIdx.x;

  if (tid < KM) {
    const float s = wsp[b * KM + tid] + wsp[KH_STRIDE + b * KM + tid];
    const int m = tid >> 6, kk = tid & 63;
    const float bias = ((m == 0) ? ba : (m == 1) ? bb : bk)[kk];
    const float e = expf(s + bias);
    if (m == 0) {
      al[kk] = e;
    } else if (m == 1) {
      bn[kk] = -LOG2E * e;
    } else {
      const float nk = prev_kappa[b * K_SZ + kk] + e;
      kap[kk] = nk;
      out_kappa[b * K_SZ + kk] = nk;
    }
  }
  __syncthreads();

  // ---- cutoff via wave-0 shfl max: term <= 2^-150 for c >= bnd ----
  if (tid < 64) {
    const float num = 150.f + fmaxf(0.f, log2f(al[tid]));
    float bv = kap[tid] + sqrtf(num / (-bn[tid]));
#pragma unroll
    for (int off = 32; off; off >>= 1)
      bv = fmaxf(bv, __shfl_xor(bv, off));
    if (tid == 0) {
      const float mx = fminf(bv, (float)C_SZ);   // sanitizes inf
      int cl = (int)mx + 1;
      cl = (cl + 15) & ~15;
      if (cl > C_SZ) cl = C_SZ;
      cl_s = cl;
    }
  }
  __syncthreads();
  const int CL = cl_s;

  // ---- T14: issue first-3 window text loads now (regs) ----
  const float4* __restrict__ t4 =
      (const float4*)(text + (size_t)b * C_SZ * A_SZ);
  const int a4 = tid & 31;   // float4 column (covers A=128)
  const int cr = tid >> 5;   // 16 parallel c-rows
  float4 tv0, tv1, tv2;
  const bool p0 = (cr      < CL);
  const bool p1 = (cr + 16 < CL);
  const bool p2 = (cr + 32 < CL);
  if (p0) tv0 = t4[(cr     ) * 32 + a4];
  if (p1) tv1 = t4[(cr + 16) * 32 + a4];
  if (p2) tv2 = t4[(cr + 32) * 32 + a4];

  // ---- phi: 4-way k-parallel, 128 c's per sweep ----
  for (int c0 = 0; c0 < CL; c0 += 128) {
    const int c = c0 + (tid & 127);
    const int kc = tid >> 7;            // 0..3
    if (c < CL) {
      const float cf = (float)c;
      float s = 0.f;
#pragma unroll
      for (int kk = kc * 16; kk < kc * 16 + 16; ++kk) {
        const float d = kap[kk] - cf;
        s += al[kk] * exp2f(bn[kk] * d * d);
      }
      pp[kc][tid & 127] = s;
    }
    __syncthreads();
    if (tid < 128) {
      const int cc = c0 + tid;
      if (cc < CL) {
        const float ph = pp[0][tid] + pp[1][tid] + pp[2][tid] + pp[3][tid];
        phi_s[cc] = ph;
        out_phi[(size_t)b * C_SZ + cc] = ph;
      }
    }
    __syncthreads();
  }
  // ---- exact zeros for c >= CL (disjoint region) ----
  {
    float4 z = make_float4(0.f, 0.f, 0.f, 0.f);
    float4* po = (float4*)(out_phi + (size_t)b * C_SZ);
    for (int i = (CL >> 2) + tid; i < C_SZ / 4; i += 512) po[i] = z;
  }

  // ---- window: preloaded rows + tail ----
  float4 acc = make_float4(0.f, 0.f, 0.f, 0.f);
  if (p0) {
    const float p = phi_s[cr];
    acc.x = fmaf(p, tv0.x, acc.x); acc.y = fmaf(p, tv0.y, acc.y);
    acc.z = fmaf(p, tv0.z, acc.z); acc.w = fmaf(p, tv0.w, acc.w);
  }
  if (p1) {
    const float p = phi_s[cr + 16];
    acc.x = fmaf(p, tv1.x, acc.x); acc.y = fmaf(p, tv1.y, acc.y);
    acc.z = fmaf(p, tv1.z, acc.z); acc.w = fmaf(p, tv1.w, acc.w);
  }
  if (p2) {
    const float p = phi_s[cr + 32];
    acc.x = fmaf(p, tv2.x, acc.x); acc.y = fmaf(p, tv2.y, acc.y);
    acc.z = fmaf(p, tv2.z, acc.z); acc.w = fmaf(p, tv2.w, acc.w);
  }
  for (int cc = cr + 48; cc < CL; cc += 16) {
    const float p = phi_s[cc];
    const float4 t = t4[cc * 32 + a4];
    acc.x = fmaf(p, t.x, acc.x); acc.y = fmaf(p, t.y, acc.y);
    acc.z = fmaf(p, t.z, acc.z); acc.w = fmaf(p, t.w, acc.w);
  }

  red[cr][a4] = acc;
  __syncthreads();

  if (tid < 32) {
    float4 w = red[0][tid];
#pragma unroll
    for (int i = 1; i < 16; ++i) {
      const float4 r = red[i][tid];
      w.x += r.x; w.y += r.y; w.z += r.z; w.w += r.w;
    }
    ((float4*)(out_window + (size_t)b * A_SZ))[tid] = w;
  }
}

extern "C" void kernel_launch(void* const* d_in, const int* in_sizes, int n_in,
                              void* d_out, int out_size, void* d_ws, size_t ws_size,
                              hipStream_t stream) {
  const float* x    = (const float*)d_in[0];
  const float* text = (const float*)d_in[1];
  const float* pk   = (const float*)d_in[2];
  const float* Wa   = (const float*)d_in[3];
  const float* ba   = (const float*)d_in[4];
  const float* Wb   = (const float*)d_in[5];
  const float* bb   = (const float*)d_in[6];
  const float* Wk   = (const float*)d_in[7];
  const float* bk   = (const float*)d_in[8];

  float* out        = (float*)d_out;
  float* out_phi    = out;                              // B*C
  float* out_kappa  = out + (size_t)B_SZ * C_SZ;        // B*K
  float* out_win    = out_kappa + (size_t)B_SZ * K_SZ;  // B*A

  float* wsp        = (float*)d_ws;                     // 2*512*192*4 = 786KB

  gw_gemm_mfma<<<768, 64, 0, stream>>>(x, Wa, Wb, Wk, wsp);
  gw_phi_window<<<B_SZ, 512, 0, stream>>>(text, wsp, pk, ba, bb, bk,
                                          out_phi, out_kappa, out_win);
}